// Round 19
// baseline (152.842 us; speedup 1.0000x reference)
//
#include <hip/hip_runtime.h>
#include <hip/hip_bf16.h>
#include <math.h>

// Problem geometry (B=2, T=1024, D=384 -> d=128, D3=384, D9=1152)
#define NTOK  2048
#define DD    128
#define DD3   384
#define DD9   1152
#define TB    2          // tokens per block in k_sig
#define TBQ   2          // tokens per block in k_qkv -> 1024 blocks
#define TBP   8          // tokens per block in k_proj -> 256 blocks
#define GAMMA_F 5.0f
#define LN2_F   0.69314718f
#define LOG2E_F 1.44269504f

// Workspace layout (float units):
#define OFF_M    0
#define OFF_C    147456
#define OFF_BP   148608
#define OFF_ATT  369792
#define OFF_QKV  765056

typedef __attribute__((ext_vector_type(8))) short bf16x8;
typedef __attribute__((ext_vector_type(4))) float f32x4;

__device__ __forceinline__ float softplusf(float x) {
    return fmaxf(x, 0.0f) + log1pf(__expf(-fabsf(x)));
}
__device__ __forceinline__ unsigned short f2bf(float f) {
    __hip_bfloat16 h = __float2bfloat16(f);
    return *reinterpret_cast<unsigned short*>(&h);
}
__device__ __forceinline__ float bf2f(unsigned short u) {
    return __uint_as_float(((unsigned)u) << 16);
}
__device__ __forceinline__ float exp2_fast(float x) {
#if __has_builtin(__builtin_amdgcn_exp2f)
    return __builtin_amdgcn_exp2f(x);
#else
    return __expf(x * LN2_F);
#endif
}

// ---------------- prep: grid 963 x 384 (r13/r17-proven)
__global__ __launch_bounds__(384) void k_prep(const float* __restrict__ Wq, const float* __restrict__ Wk,
                                              const float* __restrict__ Wv, const float* __restrict__ Wp,
                                              const float* __restrict__ Sq, const float* __restrict__ Sk,
                                              const float* __restrict__ Sv, const float* __restrict__ bq,
                                              const float* __restrict__ bk, const float* __restrict__ bv,
                                              float* __restrict__ ws) {
    __shared__ float sw[DD3];
    int b = blockIdx.x, tid = threadIdx.x;
    if (b < 576) {                        // ---- B_pack
        int idx = b * 384 + tid;
        unsigned lo = f2bf(softplusf(Wp[2 * idx + 0]) - LN2_F);
        unsigned hi = f2bf(softplusf(Wp[2 * idx + 1]) - LN2_F);
        ((unsigned*)(ws + OFF_BP))[idx] = lo | (hi << 16);
    } else if (b < 960) {                 // ---- M[i][m], interleaved-by-4 store
        int bb = b - 576;
        int mat = bb >> 7, i = bb & 127;
        const float* W = (mat == 0) ? Wq : (mat == 1 ? Wk : Wv);
        const float* S = (mat == 0) ? Sq : (mat == 1 ? Sk : Sv);
        int m = tid;
        sw[m] = softplusf(W[m * DD + i]);
        __syncthreads();
        const float4* sw4 = (const float4*)sw;
        float a0 = 0.f, a1 = 0.f, a2 = 0.f, a3 = 0.f;
        for (int j4 = 0; j4 < 96; ++j4) {
            float4 w = sw4[j4];
            int j = j4 * 4;
            a0 = fmaf(w.x, S[(j + 0) * DD3 + m], a0);
            a1 = fmaf(w.y, S[(j + 1) * DD3 + m], a1);
            a2 = fmaf(w.z, S[(j + 2) * DD3 + m], a2);
            a3 = fmaf(w.w, S[(j + 3) * DD3 + m], a3);
        }
        ws[OFF_M + mat * 49152 + (i >> 2) * (DD3 * 4) + m * 4 + (i & 3)] = (a0 + a1) + (a2 + a3);
    } else {                              // ---- c[m]
        int mat = b - 960;
        const float* S = (mat == 0) ? Sq : (mat == 1 ? Sk : Sv);
        const float* bb_ = (mat == 0) ? bq : (mat == 1 ? bk : bv);
        int m = tid;
        float a0 = 0.f, a1 = 0.f, a2 = 0.f, a3 = 0.f;
        for (int j4 = 0; j4 < 96; ++j4) {
            int j = j4 * 4;
            a0 = fmaf(bb_[j + 0], S[(j + 0) * DD3 + m], a0);
            a1 = fmaf(bb_[j + 1], S[(j + 1) * DD3 + m], a1);
            a2 = fmaf(bb_[j + 2], S[(j + 2) * DD3 + m], a2);
            a3 = fmaf(bb_[j + 3], S[(j + 3) * DD3 + m], a3);
        }
        ws[OFF_C + mat * DD3 + m] = (a0 + a1) + (a2 + a3);
    }
}

// ---------------- k_qkv: QKV projection; x-tile staged in LDS (kills per-iter scalar-load stalls)
__global__ __launch_bounds__(384, 6) void k_qkv(const float* __restrict__ x,
                                                float* __restrict__ ws) {
    __shared__ float xs[TBQ * DD3];        // 3 KB
    int tid = threadIdx.x;
    int tok0 = blockIdx.x * TBQ;
    const float* xb = x + (size_t)tok0 * DD3;
    float* qg = ws + OFF_QKV + (size_t)tok0 * DD9;

    ((float2*)xs)[tid] = ((const float2*)xb)[tid];   // 768 floats = 384 float2
    __syncthreads();

    const float4* xs4 = (const float4*)xs;
#pragma unroll
    for (int mat = 0; mat < 3; ++mat) {
        const float4* M4 = (const float4*)(ws + OFF_M + mat * 49152);
        float a0 = 0.f, a1 = 0.f;
        for (int i4 = 0; i4 < 32; ++i4) {
            float4 mm = M4[i4 * DD3 + tid];
            float4 xa = xs4[0 * 96 + mat * 32 + i4];
            float4 xbb = xs4[1 * 96 + mat * 32 + i4];
            a0 = fmaf(xa.x,  mm.x, fmaf(xa.y,  mm.y, fmaf(xa.z,  mm.z, fmaf(xa.w,  mm.w, a0))));
            a1 = fmaf(xbb.x, mm.x, fmaf(xbb.y, mm.y, fmaf(xbb.z, mm.z, fmaf(xbb.w, mm.w, a1))));
        }
        float c = ws[OFF_C + mat * DD3 + tid];
        qg[0 * DD9 + mat * DD3 + tid] = a0 + c;
        qg[1 * DD9 + mat * DD3 + tid] = a1 + c;
    }
}

// Exact sigmoid row-quad (r17-proven): 2 trans + ~4 VALU per element.
#define SIGROW(NQ, RS, AV) do {                                        \
        float e0 = exp2_fast((NQ) * kk.x);                             \
        float e1 = exp2_fast((NQ) * kk.y);                             \
        float e2 = exp2_fast((NQ) * kk.z);                             \
        float e3 = exp2_fast((NQ) * kk.w);                             \
        float s0 = __builtin_amdgcn_rcpf(1.0f + e0);                   \
        float s1 = __builtin_amdgcn_rcpf(1.0f + e1);                   \
        float s2 = __builtin_amdgcn_rcpf(1.0f + e2);                   \
        float s3 = __builtin_amdgcn_rcpf(1.0f + e3);                   \
        RS += (s0 + s1) + (s2 + s3);                                   \
        AV = fmaf(s0, vv.x, fmaf(s1, vv.y, fmaf(s2, vv.z, fmaf(s3, vv.w, AV)))); \
    } while (0)

// ---------------- k_sig: pure compute; 1-deep K/V prefetch hides uniform-load latency
__global__ __launch_bounds__(384, 6) void k_sig(float* __restrict__ ws) {
    int tid = threadIdx.x;
    int tok0 = blockIdx.x * TB;
    int t  = __builtin_amdgcn_readfirstlane(tid / 192);   // wave-uniform
    int ts = tid - t * 192;
    const float* qkvg = ws + OFF_QKV + (size_t)(tok0 + t) * DD9;

    float nq0 = qkvg[ts]       * (-GAMMA_F * LOG2E_F);
    float nq1 = qkvg[ts + 192] * (-GAMMA_F * LOG2E_F);
    const float4* K4 = (const float4*)(qkvg + DD3);       // uniform -> s_load
    const float4* V4 = (const float4*)(qkvg + 2 * DD3);
    float rs0 = 0.f, rs1 = 0.f, av0 = 0.f, av1 = 0.f;
    float4 kk = K4[0], vv = V4[0];
    for (int j4 = 0; j4 < 96; ++j4) {
        int jn = (j4 < 95) ? j4 + 1 : 95;
        float4 kn = K4[jn];
        float4 vn = V4[jn];
        SIGROW(nq0, rs0, av0);
        SIGROW(nq1, rs1, av1);
        kk = kn; vv = vn;
    }
    float a0 = av0 * __builtin_amdgcn_rcpf(rs0 + 1e-8f);
    float a1 = av1 * __builtin_amdgcn_rcpf(rs1 + 1e-8f);
    unsigned short* ag = (unsigned short*)(ws + OFF_ATT);
    ag[(size_t)(tok0 + t) * DD3 + ts]       = f2bf(a0);
    ag[(size_t)(tok0 + t) * DD3 + ts + 192] = f2bf(a1);
}

// ---------------- k_proj: MFMA from GLOBAL A/B + ssum + LN (r18-verbatim). TBP=8.
__global__ __launch_bounds__(384) void k_proj(const float* __restrict__ bp,
                                              const float* __restrict__ gn,
                                              const float* __restrict__ bn,
                                              const float* __restrict__ ws,
                                              float* __restrict__ out) {
    __shared__ float h[TBP * DD9];              // 36 KB
    __shared__ float red[64];
    __shared__ float ssum[TBP], smu[TBP], sinv[TBP];

    int tid = threadIdx.x;
    int wave = tid >> 6, lane64 = tid & 63;
    int tok0 = blockIdx.x * TBP;
    const unsigned short* ag = (const unsigned short*)(ws + OFF_ATT);

    // ---- ssum over the SAME bf16 att values the MFMA consumes (r6 consistency)
#pragma unroll
    for (int r = 0; r < TBP; ++r) {
        float s = bf2f(ag[(size_t)(tok0 + r) * DD3 + tid]);
#pragma unroll
        for (int off = 32; off; off >>= 1) s += __shfl_down(s, off, 64);
        if (lane64 == 0) red[r * 8 + wave] = s;
    }
    __syncthreads();
    if (tid < TBP) {
        float a = 0.f;
        for (int w = 0; w < 6; ++w) a += red[tid * 8 + w];
        ssum[tid] = a;
    }

    // ---- MFMA: A read directly from global (rows 8..15 alias rows 0..7 via brow&7)
    {
        int n0w  = wave * 192;
        int brow = lane64 & 15;
        int koff = (lane64 >> 4) * 8;
        const unsigned short* Bp = (const unsigned short*)(ws + OFF_BP);
        const unsigned short* abase = ag + (size_t)(tok0 + (brow & 7)) * DD3 + koff;
        const unsigned short* bbase = Bp + (size_t)(n0w + brow) * DD3 + koff;
        f32x4 acc[12];
#pragma unroll
        for (int nt = 0; nt < 12; ++nt) acc[nt] = (f32x4){0.f, 0.f, 0.f, 0.f};
        for (int ks = 0; ks < 12; ++ks) {
            bf16x8 a = *(const bf16x8*)(abase + ks * 32);
            const unsigned short* bk_ = bbase + ks * 32;
#pragma unroll
            for (int nt = 0; nt < 12; ++nt) {
                bf16x8 bfr = *(const bf16x8*)(bk_ + nt * 16 * DD3);
                acc[nt] = __builtin_amdgcn_mfma_f32_16x16x32_bf16(a, bfr, acc[nt], 0, 0, 0);
            }
        }
        // C/D: col = lane&15, row = (lane>>4)*4 + reg. Rows 0..7 live in lanes 0..31.
        if (lane64 < 32) {
            int rbase = (lane64 >> 4) * 4;
            int col0  = n0w + (lane64 & 15);
#pragma unroll
            for (int nt = 0; nt < 12; ++nt) {
#pragma unroll
                for (int r = 0; r < 4; ++r)
                    h[(rbase + r) * DD9 + col0 + nt * 16] = acc[nt][r];
            }
        }
    }
    __syncthreads();

    // ---- bias + ln2*ssum fold, two-pass LayerNorm
    float acc3[3][TBP];
    {
        float bp0 = bp[tid], bp1 = bp[tid + DD3], bp2 = bp[tid + 2 * DD3];
#pragma unroll
        for (int t = 0; t < TBP; ++t) {
            float base = LN2_F * ssum[t];
            acc3[0][t] = h[t * DD9 + tid]           + bp0 + base;
            acc3[1][t] = h[t * DD9 + tid + DD3]     + bp1 + base;
            acc3[2][t] = h[t * DD9 + tid + 2 * DD3] + bp2 + base;
        }
    }
#pragma unroll
    for (int t = 0; t < TBP; ++t) {
        float s = acc3[0][t] + acc3[1][t] + acc3[2][t];
#pragma unroll
        for (int off = 32; off; off >>= 1) s += __shfl_down(s, off, 64);
        if (lane64 == 0) red[t * 8 + wave] = s;
    }
    __syncthreads();
    if (tid < TBP) {
        float a = 0.f;
        for (int w = 0; w < 6; ++w) a += red[tid * 8 + w];
        smu[tid] = a * (1.0f / 1152.0f);
    }
    __syncthreads();
#pragma unroll
    for (int t = 0; t < TBP; ++t) {
        float mu = smu[t];
        acc3[0][t] -= mu; acc3[1][t] -= mu; acc3[2][t] -= mu;
        float s = fmaf(acc3[0][t], acc3[0][t], fmaf(acc3[1][t], acc3[1][t], acc3[2][t] * acc3[2][t]));
#pragma unroll
        for (int off = 32; off; off >>= 1) s += __shfl_down(s, off, 64);
        if (lane64 == 0) red[t * 8 + wave] = s;
    }
    __syncthreads();
    if (tid < TBP) {
        float b = 0.f;
        for (int w = 0; w < 6; ++w) b += red[tid * 8 + w];
        sinv[tid] = __builtin_amdgcn_rsqf(b * (1.0f / 1152.0f) + 1e-5f);
    }
    __syncthreads();
    float g0 = gn[tid], g1 = gn[tid + DD3], g2 = gn[tid + 2 * DD3];
    float b0 = bn[tid], b1 = bn[tid + DD3], b2 = bn[tid + 2 * DD3];
#pragma unroll
    for (int t = 0; t < TBP; ++t) {
        float inv = sinv[t];
        size_t base = (size_t)(tok0 + t) * DD9;
        out[base + tid]           = fmaf(acc3[0][t] * inv, g0, b0);
        out[base + tid + DD3]     = fmaf(acc3[1][t] * inv, g1, b1);
        out[base + tid + 2 * DD3] = fmaf(acc3[2][t] * inv, g2, b2);
    }
}

extern "C" void kernel_launch(void* const* d_in, const int* in_sizes, int n_in,
                              void* d_out, int out_size, void* d_ws, size_t ws_size,
                              hipStream_t stream) {
    const float* x  = (const float*)d_in[0];
    const float* Wq = (const float*)d_in[1];
    const float* bq = (const float*)d_in[2];
    const float* Sq = (const float*)d_in[3];
    const float* Wk = (const float*)d_in[4];
    const float* bk = (const float*)d_in[5];
    const float* Sk = (const float*)d_in[6];
    const float* Wv = (const float*)d_in[7];
    const float* bv = (const float*)d_in[8];
    const float* Sv = (const float*)d_in[9];
    const float* Wp = (const float*)d_in[10];
    const float* bp = (const float*)d_in[11];
    const float* gn = (const float*)d_in[12];
    const float* bn = (const float*)d_in[13];
    float* out = (float*)d_out;
    float* ws  = (float*)d_ws;

    hipLaunchKernelGGL(k_prep, dim3(963), dim3(384), 0, stream,
                       Wq, Wk, Wv, Wp, Sq, Sk, Sv, bq, bk, bv, ws);
    hipLaunchKernelGGL(k_qkv, dim3(NTOK / TBQ), dim3(384), 0, stream, x, ws);
    hipLaunchKernelGGL(k_sig, dim3(NTOK / TB), dim3(384), 0, stream, ws);
    hipLaunchKernelGGL(k_proj, dim3(NTOK / TBP), dim3(384), 0, stream, bp, gn, bn, ws, out);
}